// Round 1
// baseline (1554.595 us; speedup 1.0000x reference)
//
#include <hip/hip_runtime.h>

#define NE 8
#define NT 4096
#define NH 2048

typedef unsigned short u16_t;
typedef unsigned int u32_t;
typedef __attribute__((ext_vector_type(8))) short short8;    // 8 bf16 (4 VGPRs)
typedef __attribute__((ext_vector_type(4))) float floatx4;   // MFMA C/D

// f32 -> bf16, round-to-nearest-even (exact for ints |v|<=256, i.e. the weights)
static __device__ __forceinline__ u16_t f2bf(float f) {
  union { float fv; u32_t uv; } v; v.fv = f;
  u32_t r = v.uv + 0x7fffu + ((v.uv >> 16) & 1u);
  return (u16_t)(r >> 16);
}

// w[e][k][n] int32 -> wt8[e][k/8][n][8] bf16  (k-chunk-blocked "transpose")
// Reads: 8 lane-coalesced dword loads (stride N). Writes: fully coalesced uint4.
__global__ void cvt_w_kernel(const int* __restrict__ w, u16_t* __restrict__ wt) {
  size_t g = (size_t)blockIdx.x * 256 + threadIdx.x;
  const int n  = (int)(g & (NH - 1));
  const int k8 = (int)((g >> 11) & (NH / 8 - 1));
  const int e  = (int)(g >> 19);
  const int* src = w + ((size_t)e * NH + (size_t)k8 * 8) * NH + n;
  u32_t p[4];
#pragma unroll
  for (int j = 0; j < 4; ++j) {
    u32_t lo = (u32_t)f2bf((float)src[(size_t)(2 * j) * NH]);
    u32_t hi = (u32_t)f2bf((float)src[(size_t)(2 * j + 1) * NH]);
    p[j] = lo | (hi << 16);
  }
  uint4 v; v.x = p[0]; v.y = p[1]; v.z = p[2]; v.w = p[3];
  *(uint4*)(wt + (((size_t)e * (NH / 8) + k8) * NH + n) * 8) = v;
}

// C[e][m][n] = (A[e][m][k] @ B[e][k][n]) * scale[e][n]
// A: f32 (layer1, converted during staging) or bf16. BT8: blocked bf16 weights.
// 128x128 tile, BK=32, 4 waves each doing 4x4 of 16x16x32 MFMA.
template <typename AT, typename OT>
__global__ __launch_bounds__(256)
void gemm_bt_kernel(const AT* __restrict__ A, const u16_t* __restrict__ BT8,
                    const float* __restrict__ scale, OT* __restrict__ C) {
  constexpr int M = NT, N = NH, K = NH;
  const int e  = blockIdx.z;
  const int n0 = blockIdx.x * 128;
  const int m0 = blockIdx.y * 128;
  const int tid  = (int)threadIdx.x;
  const int lane = tid & 63, wv = tid >> 6;
  const int wm = (wv & 1) * 64, wn = (wv >> 1) * 64;
  const int quad = lane >> 4, l16 = lane & 15;

  const AT* Ae = A + (size_t)e * M * K;
  const u16_t* Be = BT8 + (size_t)e * (K / 8) * (size_t)N * 8;
  const float* se = scale + (size_t)e * N;
  OT* Ce = C + (size_t)e * (size_t)M * N;

  // pitch 40 ushorts = 80 B (16B-aligned rows; frag reads ~2-way conflict = free)
  __shared__ __align__(16) u16_t Al[128 * 40];
  __shared__ __align__(16) u16_t Bl[128 * 40];

  const int ar  = tid >> 2;          // A row job0 (job1 = +64)
  const int akc = (tid & 3) * 8;     // A k-chunk offset (elems)
  const int bn  = tid & 127;         // B row (n)
  const int bk8 = tid >> 7;          // B k8 job0 (job1 = +2)

  floatx4 acc[4][4] = {};

  auto loadA = [&](int k0, int r) -> uint4 {
    const int row = ar + r * 64;
    if constexpr (sizeof(AT) == 4) {
      const float* p = (const float*)Ae + (size_t)(m0 + row) * K + k0 + akc;
      float4 x0 = *(const float4*)p;
      float4 x1 = *(const float4*)(p + 4);
      uint4 o;
      o.x = (u32_t)f2bf(x0.x) | ((u32_t)f2bf(x0.y) << 16);
      o.y = (u32_t)f2bf(x0.z) | ((u32_t)f2bf(x0.w) << 16);
      o.z = (u32_t)f2bf(x1.x) | ((u32_t)f2bf(x1.y) << 16);
      o.w = (u32_t)f2bf(x1.z) | ((u32_t)f2bf(x1.w) << 16);
      return o;
    } else {
      return *(const uint4*)((const u16_t*)Ae + (size_t)(m0 + row) * K + k0 + akc);
    }
  };
  auto loadB = [&](int k0, int r) -> uint4 {
    const size_t k8 = (size_t)(k0 >> 3) + bk8 + r * 2;
    return *(const uint4*)(Be + (k8 * N + (size_t)(n0 + bn)) * 8);
  };

  uint4 avr0 = loadA(0, 0), avr1 = loadA(0, 1);
  uint4 bvr0 = loadB(0, 0), bvr1 = loadB(0, 1);

  for (int kt = 0; kt < K / 32; ++kt) {
    __syncthreads();
    *(uint4*)&Al[ar * 40 + akc]        = avr0;
    *(uint4*)&Al[(ar + 64) * 40 + akc] = avr1;
    *(uint4*)&Bl[bn * 40 + bk8 * 8]       = bvr0;
    *(uint4*)&Bl[bn * 40 + (bk8 + 2) * 8] = bvr1;
    __syncthreads();

    // register-prefetch next K-tile (overlaps MFMA below)
    const int kn = ((kt + 1) & (K / 32 - 1)) * 32;
    avr0 = loadA(kn, 0); avr1 = loadA(kn, 1);
    bvr0 = loadB(kn, 0); bvr1 = loadB(kn, 1);

    short8 af[4], bfr[4];
#pragma unroll
    for (int i = 0; i < 4; ++i)
      af[i] = *(const short8*)&Al[(wm + i * 16 + l16) * 40 + quad * 8];
#pragma unroll
    for (int j = 0; j < 4; ++j)
      bfr[j] = *(const short8*)&Bl[(wn + j * 16 + l16) * 40 + quad * 8];
#pragma unroll
    for (int i = 0; i < 4; ++i)
#pragma unroll
      for (int j = 0; j < 4; ++j)
        acc[i][j] = __builtin_amdgcn_mfma_f32_16x16x32_bf16(af[i], bfr[j], acc[i][j], 0, 0, 0);
  }

  float scl[4];
#pragma unroll
  for (int j = 0; j < 4; ++j) scl[j] = se[n0 + wn + j * 16 + l16];
#pragma unroll
  for (int i = 0; i < 4; ++i) {
#pragma unroll
    for (int r = 0; r < 4; ++r) {
      const int row = m0 + wm + i * 16 + quad * 4 + r;
#pragma unroll
      for (int j = 0; j < 4; ++j) {
        const float v = acc[i][j][r] * scl[j];
        const int col = n0 + wn + j * 16 + l16;
        if constexpr (sizeof(OT) == 2) {
          Ce[(size_t)row * N + col] = f2bf(v);   // h as bf16
        } else {
          Ce[(size_t)row * N + col] = v;         // final out f32
        }
      }
    }
  }
}

extern "C" void kernel_launch(void* const* d_in, const int* in_sizes, int n_in,
                              void* d_out, int out_size, void* d_ws, size_t ws_size,
                              hipStream_t stream) {
  const float* x   = (const float*)d_in[0];
  const int*   w1q = (const int*)d_in[1];
  const float* s1  = (const float*)d_in[2];
  const int*   w2q = (const int*)d_in[3];
  const float* s2  = (const float*)d_in[4];
  float* out = (float*)d_out;

  // ws layout: h (E*T*H bf16 = 128 MiB) | wt (E*H*H bf16 = 64 MiB, reused per layer)
  u16_t* h  = (u16_t*)d_ws;
  u16_t* wt = (u16_t*)d_ws + (size_t)NE * NT * NH;

  const int cvt_blocks = (NE * (NH / 8) * NH) / 256;   // 16384
  dim3 ggrid(NH / 128, NT / 128, NE);                  // 16 x 32 x 8

  cvt_w_kernel<<<cvt_blocks, 256, 0, stream>>>(w1q, wt);
  gemm_bt_kernel<float, u16_t><<<ggrid, 256, 0, stream>>>(x, wt, s1, h);
  cvt_w_kernel<<<cvt_blocks, 256, 0, stream>>>(w2q, wt);
  gemm_bt_kernel<u16_t, float><<<ggrid, 256, 0, stream>>>(h, wt, s2, out);
}